// Round 1
// baseline (963.712 us; speedup 1.0000x reference)
//
#include <hip/hip_runtime.h>

#define NN 100000
#define NE 1600000

constexpr int F_IN = 58;
constexpr int F_H  = 16;   // per stack
constexpr int KS   = 2;
constexpr int FH2  = 32;   // KS * F_H
constexpr int NODES_PER_BLK = 8;

__global__ void k_zero(float* __restrict__ p, int n) {
    int i = blockIdx.x * blockDim.x + threadIdx.x;
    if (i < n) p[i] = 0.f;
}

__global__ void k_deg(const int* __restrict__ col, float* __restrict__ deg) {
    int e = blockIdx.x * blockDim.x + threadIdx.x;
    if (e < NE) atomicAdd(&deg[col[e]], 1.0f);
}

__global__ void k_dis(const float* __restrict__ deg, float* __restrict__ dis) {
    int n = blockIdx.x * blockDim.x + threadIdx.x;
    if (n < NN) {
        float d = deg[n];
        dis[n] = (d > 0.f) ? rsqrtf(d) : 0.f;   // max(deg,1) no-op when deg>=1
    }
}

__global__ void k_norm(const int* __restrict__ row, const int* __restrict__ col,
                       const float* __restrict__ dis, float* __restrict__ nrm) {
    int e = blockIdx.x * blockDim.x + threadIdx.x;
    if (e < NE) nrm[e] = dis[row[e]] * dis[col[e]];
}

// h1[n][ko] = sum_i x[n][i]*Wi[k][i][o];  acc1[n][ko] = sum_i x[n][i]*Wr[k][i][o] + b[k][o]
// ko = k*16+o. One thread per (node, ko); 8 nodes per 256-thread block.
__global__ void k_dense1(const float* __restrict__ x,
                         const float* __restrict__ Wi, const float* __restrict__ Wr,
                         const float* __restrict__ b,
                         float* __restrict__ h1, float* __restrict__ acc1) {
    __shared__ float swi[F_IN * FH2];
    __shared__ float swr[F_IN * FH2];
    __shared__ float sx[NODES_PER_BLK * F_IN];
    int tid = threadIdx.x;
    for (int t = tid; t < F_IN * FH2; t += 256) {
        int i = t >> 5, ko = t & 31;
        int k = ko >> 4, o = ko & 15;
        swi[t] = Wi[(k * F_IN + i) * F_H + o];
        swr[t] = Wr[(k * F_IN + i) * F_H + o];
    }
    int nodeBase = blockIdx.x * NODES_PER_BLK;
    for (int t = tid; t < NODES_PER_BLK * F_IN; t += 256) {
        int ln = t / F_IN, i = t - ln * F_IN;
        int n = nodeBase + ln;
        sx[t] = (n < NN) ? x[n * F_IN + i] : 0.f;
    }
    __syncthreads();
    int ln = tid >> 5, ko = tid & 31;
    int n = nodeBase + ln;
    if (n >= NN) return;
    float hi = 0.f, hr = 0.f;
    const float* xr = &sx[ln * F_IN];
#pragma unroll
    for (int i = 0; i < F_IN; i++) {
        float xv = xr[i];
        hi = fmaf(xv, swi[i * FH2 + ko], hi);
        hr = fmaf(xv, swr[i * FH2 + ko], hr);
    }
    h1[n * FH2 + ko] = hi;
    acc1[n * FH2 + ko] = hr + b[ko];   // b layout [2][16] == [ko]
}

// per (edge, chunk-of-4): acc1[col] += nrm * h1[row]
__global__ void k_scatter1(const int* __restrict__ row, const int* __restrict__ col,
                           const float* __restrict__ nrm,
                           const float* __restrict__ h1, float* __restrict__ acc1) {
    int tid = blockIdx.x * blockDim.x + threadIdx.x;
    int e = tid >> 3, c = tid & 7;
    if (e >= NE) return;
    float w = nrm[e];
    if (w == 0.f) return;
    int r = row[e], t = col[e];
    const float4 v = *(const float4*)&h1[r * FH2 + c * 4];
    float* a = &acc1[t * FH2 + c * 4];
    atomicAdd(a + 0, w * v.x);
    atomicAdd(a + 1, w * v.y);
    atomicAdd(a + 2, w * v.z);
    atomicAdd(a + 3, w * v.w);
}

// finish layer1 (relu + mean over k), then dense layer2 (16 -> 1, K=2)
__global__ void k_mid(const float* __restrict__ acc1,
                      const float* __restrict__ Wi2, const float* __restrict__ Wr2,
                      const float* __restrict__ b2,
                      float* __restrict__ h2, float* __restrict__ acc2) {
    int n = blockIdx.x * blockDim.x + threadIdx.x;
    if (n >= NN) return;
    float h[F_H];
    const float* a = &acc1[n * FH2];
#pragma unroll
    for (int f = 0; f < F_H; f++) {
        float v0 = fmaxf(a[f], 0.f);
        float v1 = fmaxf(a[F_H + f], 0.f);
        h[f] = 0.5f * (v0 + v1);   // mean over K=2; wrapper relu is identity (h>=0)
    }
#pragma unroll
    for (int k = 0; k < KS; k++) {
        float s1 = 0.f, s2 = 0.f;
#pragma unroll
        for (int f = 0; f < F_H; f++) {
            s1 = fmaf(h[f], Wi2[k * F_H + f], s1);
            s2 = fmaf(h[f], Wr2[k * F_H + f], s2);
        }
        h2[n * KS + k] = s1;
        acc2[n * KS + k] = s2 + b2[k];
    }
}

__global__ void k_scatter2(const int* __restrict__ row, const int* __restrict__ col,
                           const float* __restrict__ nrm,
                           const float* __restrict__ h2, float* __restrict__ acc2) {
    int e = blockIdx.x * blockDim.x + threadIdx.x;
    if (e >= NE) return;
    float w = nrm[e];
    if (w == 0.f) return;
    int r = row[e], t = col[e];
    atomicAdd(&acc2[t * 2 + 0], w * h2[r * 2 + 0]);
    atomicAdd(&acc2[t * 2 + 1], w * h2[r * 2 + 1]);
}

__global__ void k_out(const float* __restrict__ acc2, float* __restrict__ out) {
    int n = blockIdx.x * blockDim.x + threadIdx.x;
    if (n >= NN) return;
    out[n] = 0.5f * (fmaxf(acc2[n * 2 + 0], 0.f) + fmaxf(acc2[n * 2 + 1], 0.f));
}

extern "C" void kernel_launch(void* const* d_in, const int* in_sizes, int n_in,
                              void* d_out, int out_size, void* d_ws, size_t ws_size,
                              hipStream_t stream) {
    const float* x   = (const float*)d_in[0];
    const int*   ei  = (const int*)d_in[1];
    const float* Wi1 = (const float*)d_in[2];
    const float* Wr1 = (const float*)d_in[3];
    const float* b1  = (const float*)d_in[4];
    const float* Wi2 = (const float*)d_in[5];
    const float* Wr2 = (const float*)d_in[6];
    const float* b2  = (const float*)d_in[7];
    float* out = (float*)d_out;

    const int* row = ei;            // edge_index[0]
    const int* col = ei + NE;       // edge_index[1]

    float* ws = (float*)d_ws;
    float* deg  = ws;                         // NN
    float* dis  = deg + NN;                   // NN
    float* nrm  = dis + NN;                   // NE
    float* h1   = nrm + NE;                   // NN*32
    float* acc1 = h1 + (size_t)NN * FH2;      // NN*32
    float* h2   = acc1 + (size_t)NN * FH2;    // NN*2
    float* acc2 = h2 + (size_t)NN * KS;       // NN*2

    const int B = 256;
    k_zero<<<(NN + B - 1) / B, B, 0, stream>>>(deg, NN);
    k_deg<<<(NE + B - 1) / B, B, 0, stream>>>(col, deg);
    k_dis<<<(NN + B - 1) / B, B, 0, stream>>>(deg, dis);
    k_norm<<<(NE + B - 1) / B, B, 0, stream>>>(row, col, dis, nrm);
    k_dense1<<<(NN + NODES_PER_BLK - 1) / NODES_PER_BLK, B, 0, stream>>>(x, Wi1, Wr1, b1, h1, acc1);
    {
        long tot = (long)NE * 8;
        k_scatter1<<<(int)((tot + B - 1) / B), B, 0, stream>>>(row, col, nrm, h1, acc1);
    }
    k_mid<<<(NN + B - 1) / B, B, 0, stream>>>(acc1, Wi2, Wr2, b2, h2, acc2);
    k_scatter2<<<(NE + B - 1) / B, B, 0, stream>>>(row, col, nrm, h2, acc2);
    k_out<<<(NN + B - 1) / B, B, 0, stream>>>(acc2, out);
}

// Round 2
// 273.011 us; speedup vs baseline: 3.5299x; 3.5299x over previous
//
#include <hip/hip_runtime.h>

#define NN 100000
#define NE 1600000

constexpr int F_IN = 58;
constexpr int F_H  = 16;
constexpr int KS   = 2;
constexpr int FH2  = 32;   // KS * F_H
constexpr int NODES_PER_BLK = 8;

constexpr int SCAN_B = 256;                      // threads per scan block
constexpr int SCAN_E = 1024;                     // elements per scan block
constexpr int NSCAN  = (NN + SCAN_E - 1) / SCAN_E;  // 98 blocks

__global__ void k_zero_int(int* __restrict__ p, int n) {
    int i = blockIdx.x * blockDim.x + threadIdx.x;
    if (i < n) p[i] = 0;
}

__global__ void k_count(const int* __restrict__ col, int* __restrict__ cnt) {
    int e = blockIdx.x * blockDim.x + threadIdx.x;
    if (e < NE) atomicAdd(&cnt[col[e]], 1);
}

__global__ void k_dis(const int* __restrict__ cnt, float* __restrict__ dis) {
    int n = blockIdx.x * blockDim.x + threadIdx.x;
    if (n < NN) {
        int c = cnt[n];
        dis[n] = (c > 0) ? rsqrtf((float)c) : 0.f;
    }
}

// inclusive scan, stage 1: per-block scan of 1024 elements
__global__ void k_scan1(const int* __restrict__ cnt, int* __restrict__ inc,
                        int* __restrict__ bsum) {
    __shared__ int ts[SCAN_B];
    int tid = threadIdx.x;
    int base = blockIdx.x * SCAN_E + tid * 4;
    int v0 = (base + 0 < NN) ? cnt[base + 0] : 0;
    int v1 = (base + 1 < NN) ? cnt[base + 1] : 0;
    int v2 = (base + 2 < NN) ? cnt[base + 2] : 0;
    int v3 = (base + 3 < NN) ? cnt[base + 3] : 0;
    int p0 = v0, p1 = p0 + v1, p2 = p1 + v2, p3 = p2 + v3;
    ts[tid] = p3;
    __syncthreads();
    for (int off = 1; off < SCAN_B; off <<= 1) {
        int v = (tid >= off) ? ts[tid - off] : 0;
        __syncthreads();
        ts[tid] += v;
        __syncthreads();
    }
    int prev = (tid > 0) ? ts[tid - 1] : 0;
    if (base + 0 < NN) inc[base + 0] = prev + p0;
    if (base + 1 < NN) inc[base + 1] = prev + p1;
    if (base + 2 < NN) inc[base + 2] = prev + p2;
    if (base + 3 < NN) inc[base + 3] = prev + p3;
    if (tid == SCAN_B - 1) bsum[blockIdx.x] = ts[SCAN_B - 1];
}

// stage 2: exclusive scan of block sums (single block, NSCAN <= 128)
__global__ void k_scan2(const int* __restrict__ bsum, int* __restrict__ boff) {
    __shared__ int s[128];
    int tid = threadIdx.x;
    s[tid] = (tid < NSCAN) ? bsum[tid] : 0;
    __syncthreads();
    for (int off = 1; off < 128; off <<= 1) {
        int v = (tid >= off) ? s[tid - off] : 0;
        __syncthreads();
        s[tid] += v;
        __syncthreads();
    }
    if (tid < NSCAN) boff[tid] = (tid > 0) ? s[tid - 1] : 0;
}

// stage 3: add block offsets -> full inclusive scan in `inc`
__global__ void k_scan3(int* __restrict__ inc, const int* __restrict__ boff) {
    int i = blockIdx.x * blockDim.x + threadIdx.x;
    if (i < NN) inc[i] += boff[i >> 10];
}

// scatter edges into CSR-by-destination: ecsr[pos] = (src, norm)
__global__ void k_fill(const int* __restrict__ row, const int* __restrict__ col,
                       const float* __restrict__ dis, const int* __restrict__ inc,
                       int* __restrict__ cur, int2* __restrict__ ecsr) {
    int e = blockIdx.x * blockDim.x + threadIdx.x;
    if (e >= NE) return;
    int r = row[e], c = col[e];
    float w = dis[r] * dis[c];
    int start = (c == 0) ? 0 : inc[c - 1];
    int pos = start + atomicAdd(&cur[c], 1);
    ecsr[pos] = make_int2(r, __float_as_int(w));
}

// h1[n][ko] = x[n]·Wi[k][:,o];  a1[n][ko] = x[n]·Wr[k][:,o] + b[k][o]
__global__ void k_dense1(const float* __restrict__ x,
                         const float* __restrict__ Wi, const float* __restrict__ Wr,
                         const float* __restrict__ b,
                         float* __restrict__ h1, float* __restrict__ a1) {
    __shared__ float swi[F_IN * FH2];
    __shared__ float swr[F_IN * FH2];
    __shared__ float sx[NODES_PER_BLK * F_IN];
    int tid = threadIdx.x;
    for (int t = tid; t < F_IN * FH2; t += 256) {
        int i = t >> 5, ko = t & 31;
        int k = ko >> 4, o = ko & 15;
        swi[t] = Wi[(k * F_IN + i) * F_H + o];
        swr[t] = Wr[(k * F_IN + i) * F_H + o];
    }
    int nodeBase = blockIdx.x * NODES_PER_BLK;
    for (int t = tid; t < NODES_PER_BLK * F_IN; t += 256) {
        int ln = t / F_IN, i = t - ln * F_IN;
        int n = nodeBase + ln;
        sx[t] = (n < NN) ? x[n * F_IN + i] : 0.f;
    }
    __syncthreads();
    int ln = tid >> 5, ko = tid & 31;
    int n = nodeBase + ln;
    if (n >= NN) return;
    float hi = 0.f, hr = 0.f;
    const float* xr = &sx[ln * F_IN];
#pragma unroll
    for (int i = 0; i < F_IN; i++) {
        float xv = xr[i];
        hi = fmaf(xv, swi[i * FH2 + ko], hi);
        hr = fmaf(xv, swr[i * FH2 + ko], hr);
    }
    h1[n * FH2 + ko] = hi;
    a1[n * FH2 + ko] = hr + b[ko];
}

// pull aggregation layer1: a1[n][ko] = relu(a1_root + sum_j w_j * h1[src_j][ko])
__global__ void k_gather1(const int* __restrict__ inc, const int2* __restrict__ ecsr,
                          const float* __restrict__ h1, float* __restrict__ a1) {
    int tid = blockIdx.x * blockDim.x + threadIdx.x;
    int n = tid >> 5, ko = tid & 31;
    if (n >= NN) return;
    int js = (n == 0) ? 0 : inc[n - 1];
    int je = inc[n];
    float acc = a1[n * FH2 + ko];
    int j = js;
    // unroll by 2 for load-latency overlap
    for (; j + 1 < je; j += 2) {
        int2 e0 = ecsr[j], e1 = ecsr[j + 1];
        float v0 = h1[e0.x * FH2 + ko];
        float v1 = h1[e1.x * FH2 + ko];
        acc = fmaf(__int_as_float(e0.y), v0, acc);
        acc = fmaf(__int_as_float(e1.y), v1, acc);
    }
    if (j < je) {
        int2 e0 = ecsr[j];
        acc = fmaf(__int_as_float(e0.y), h1[e0.x * FH2 + ko], acc);
    }
    a1[n * FH2 + ko] = fmaxf(acc, 0.f);
}

// relu'd a1 -> mean over K -> dense2: h2[n][k], r2[n][k] = root2 + b2
__global__ void k_mid(const float* __restrict__ a1,
                      const float* __restrict__ Wi2, const float* __restrict__ Wr2,
                      const float* __restrict__ b2,
                      float* __restrict__ h2, float* __restrict__ r2) {
    int n = blockIdx.x * blockDim.x + threadIdx.x;
    if (n >= NN) return;
    float h[F_H];
    const float* a = &a1[n * FH2];
#pragma unroll
    for (int f = 0; f < F_H; f++)
        h[f] = 0.5f * (a[f] + a[F_H + f]);   // already relu'd; wrapper relu identity
#pragma unroll
    for (int k = 0; k < KS; k++) {
        float s1 = 0.f, s2 = 0.f;
#pragma unroll
        for (int f = 0; f < F_H; f++) {
            s1 = fmaf(h[f], Wi2[k * F_H + f], s1);
            s2 = fmaf(h[f], Wr2[k * F_H + f], s2);
        }
        h2[n * KS + k] = s1;
        r2[n * KS + k] = s2 + b2[k];
    }
}

// pull aggregation layer2 + final relu-mean -> out
__global__ void k_gather2(const int* __restrict__ inc, const int2* __restrict__ ecsr,
                          const float* __restrict__ h2, const float* __restrict__ r2,
                          float* __restrict__ out) {
    int n = blockIdx.x * blockDim.x + threadIdx.x;
    if (n >= NN) return;
    int js = (n == 0) ? 0 : inc[n - 1];
    int je = inc[n];
    float a0 = r2[n * 2 + 0], a1v = r2[n * 2 + 1];
    for (int j = js; j < je; j++) {
        int2 e = ecsr[j];
        float w = __int_as_float(e.y);
        float2 hv = *(const float2*)&h2[e.x * 2];
        a0  = fmaf(w, hv.x, a0);
        a1v = fmaf(w, hv.y, a1v);
    }
    out[n] = 0.5f * (fmaxf(a0, 0.f) + fmaxf(a1v, 0.f));
}

extern "C" void kernel_launch(void* const* d_in, const int* in_sizes, int n_in,
                              void* d_out, int out_size, void* d_ws, size_t ws_size,
                              hipStream_t stream) {
    const float* x   = (const float*)d_in[0];
    const int*   ei  = (const int*)d_in[1];
    const float* Wi1 = (const float*)d_in[2];
    const float* Wr1 = (const float*)d_in[3];
    const float* b1  = (const float*)d_in[4];
    const float* Wi2 = (const float*)d_in[5];
    const float* Wr2 = (const float*)d_in[6];
    const float* b2  = (const float*)d_in[7];
    float* out = (float*)d_out;

    const int* row = ei;
    const int* col = ei + NE;

    // workspace layout (4-byte units)
    char* wsb = (char*)d_ws;
    int*   cnt  = (int*)wsb;                         // NN
    int*   cur  = cnt + NN;                          // NN (contiguous after cnt)
    int*   inc  = cur + NN;                          // NN
    int*   bsum = inc + NN;                          // 128
    int*   boff = bsum + 128;                        // 128
    float* dis  = (float*)(boff + 128);              // NN
    int2*  ecsr = (int2*)(dis + NN);                 // NE int2 (8B aligned)
    float* h1   = (float*)(ecsr + NE);               // NN*32
    float* a1   = h1 + (size_t)NN * FH2;             // NN*32
    float* h2   = a1 + (size_t)NN * FH2;             // NN*2
    float* r2   = h2 + (size_t)NN * KS;              // NN*2

    const int B = 256;
    k_zero_int<<<(2 * NN + B - 1) / B, B, 0, stream>>>(cnt, 2 * NN);  // cnt + cur
    k_count<<<(NE + B - 1) / B, B, 0, stream>>>(col, cnt);
    k_dis<<<(NN + B - 1) / B, B, 0, stream>>>(cnt, dis);
    k_scan1<<<NSCAN, SCAN_B, 0, stream>>>(cnt, inc, bsum);
    k_scan2<<<1, 128, 0, stream>>>(bsum, boff);
    k_scan3<<<(NN + B - 1) / B, B, 0, stream>>>(inc, boff);
    k_fill<<<(NE + B - 1) / B, B, 0, stream>>>(row, col, dis, inc, cur, ecsr);
    k_dense1<<<(NN + NODES_PER_BLK - 1) / NODES_PER_BLK, B, 0, stream>>>(x, Wi1, Wr1, b1, h1, a1);
    k_gather1<<<(NN * 32 + B - 1) / B, B, 0, stream>>>(inc, ecsr, h1, a1);
    k_mid<<<(NN + B - 1) / B, B, 0, stream>>>(a1, Wi2, Wr2, b2, h2, r2);
    k_gather2<<<(NN + B - 1) / B, B, 0, stream>>>(inc, ecsr, h2, r2, out);
}

// Round 3
// 227.686 us; speedup vs baseline: 4.2326x; 1.1991x over previous
//
#include <hip/hip_runtime.h>

#define NN 100000
#define NE 1600000

constexpr int F_IN = 58;
constexpr int F_H  = 16;
constexpr int KS   = 2;
constexpr int FH2  = 32;   // KS * F_H
constexpr int NODES_PER_BLK = 8;

constexpr int SCAN_B = 256;
constexpr int SCAN_E = 1024;
constexpr int NSCAN  = (NN + SCAN_E - 1) / SCAN_E;  // 98

// histogram of destinations; atomic return value = edge's rank within its dst
__global__ void k_count_rank(const int* __restrict__ col, int* __restrict__ cnt,
                             int* __restrict__ rank) {
    int e = blockIdx.x * blockDim.x + threadIdx.x;
    if (e < NE) rank[e] = atomicAdd(&cnt[col[e]], 1);
}

// inclusive scan stage 1 (+ fused dis = rsqrt(deg))
__global__ void k_scan1(const int* __restrict__ cnt, int* __restrict__ inc,
                        int* __restrict__ bsum, float* __restrict__ dis) {
    __shared__ int ts[SCAN_B];
    int tid = threadIdx.x;
    int base = blockIdx.x * SCAN_E + tid * 4;
    int v0 = (base + 0 < NN) ? cnt[base + 0] : 0;
    int v1 = (base + 1 < NN) ? cnt[base + 1] : 0;
    int v2 = (base + 2 < NN) ? cnt[base + 2] : 0;
    int v3 = (base + 3 < NN) ? cnt[base + 3] : 0;
    if (base + 0 < NN) dis[base + 0] = (v0 > 0) ? rsqrtf((float)v0) : 0.f;
    if (base + 1 < NN) dis[base + 1] = (v1 > 0) ? rsqrtf((float)v1) : 0.f;
    if (base + 2 < NN) dis[base + 2] = (v2 > 0) ? rsqrtf((float)v2) : 0.f;
    if (base + 3 < NN) dis[base + 3] = (v3 > 0) ? rsqrtf((float)v3) : 0.f;
    int p0 = v0, p1 = p0 + v1, p2 = p1 + v2, p3 = p2 + v3;
    ts[tid] = p3;
    __syncthreads();
    for (int off = 1; off < SCAN_B; off <<= 1) {
        int v = (tid >= off) ? ts[tid - off] : 0;
        __syncthreads();
        ts[tid] += v;
        __syncthreads();
    }
    int prev = (tid > 0) ? ts[tid - 1] : 0;
    if (base + 0 < NN) inc[base + 0] = prev + p0;
    if (base + 1 < NN) inc[base + 1] = prev + p1;
    if (base + 2 < NN) inc[base + 2] = prev + p2;
    if (base + 3 < NN) inc[base + 3] = prev + p3;
    if (tid == SCAN_B - 1) bsum[blockIdx.x] = ts[SCAN_B - 1];
}

__global__ void k_scan2(const int* __restrict__ bsum, int* __restrict__ boff) {
    __shared__ int s[128];
    int tid = threadIdx.x;
    s[tid] = (tid < NSCAN) ? bsum[tid] : 0;
    __syncthreads();
    for (int off = 1; off < 128; off <<= 1) {
        int v = (tid >= off) ? s[tid - off] : 0;
        __syncthreads();
        s[tid] += v;
        __syncthreads();
    }
    if (tid < NSCAN) boff[tid] = (tid > 0) ? s[tid - 1] : 0;
}

__global__ void k_scan3(int* __restrict__ inc, const int* __restrict__ boff) {
    int i = blockIdx.x * blockDim.x + threadIdx.x;
    if (i < NN) inc[i] += boff[i >> 10];
}

// CSR fill: no atomics — position from scan + rank
__global__ void k_fill(const int* __restrict__ row, const int* __restrict__ col,
                       const float* __restrict__ dis, const int* __restrict__ inc,
                       const int* __restrict__ rank, int2* __restrict__ ecsr) {
    int e = blockIdx.x * blockDim.x + threadIdx.x;
    if (e >= NE) return;
    int r = row[e], c = col[e];
    float w = dis[r] * dis[c];
    int pos = ((c == 0) ? 0 : inc[c - 1]) + rank[e];
    ecsr[pos] = make_int2(r, __float_as_int(w));
}

// h1[n][ko] = x[n]·Wi[k][:,o];  r1[n][ko] = x[n]·Wr[k][:,o] + b[k][o]
__global__ void k_dense1(const float* __restrict__ x,
                         const float* __restrict__ Wi, const float* __restrict__ Wr,
                         const float* __restrict__ b,
                         float* __restrict__ h1, float* __restrict__ r1) {
    __shared__ float swi[F_IN * FH2];
    __shared__ float swr[F_IN * FH2];
    __shared__ float sx[NODES_PER_BLK * F_IN];
    int tid = threadIdx.x;
    for (int t = tid; t < F_IN * FH2; t += 256) {
        int i = t >> 5, ko = t & 31;
        int k = ko >> 4, o = ko & 15;
        swi[t] = Wi[(k * F_IN + i) * F_H + o];
        swr[t] = Wr[(k * F_IN + i) * F_H + o];
    }
    int nodeBase = blockIdx.x * NODES_PER_BLK;
    for (int t = tid; t < NODES_PER_BLK * F_IN; t += 256) {
        int ln = t / F_IN, i = t - ln * F_IN;
        int n = nodeBase + ln;
        sx[t] = (n < NN) ? x[n * F_IN + i] : 0.f;
    }
    __syncthreads();
    int ln = tid >> 5, ko = tid & 31;
    int n = nodeBase + ln;
    if (n >= NN) return;
    float hi = 0.f, hr = 0.f;
    const float* xr = &sx[ln * F_IN];
#pragma unroll
    for (int i = 0; i < F_IN; i++) {
        float xv = xr[i];
        hi = fmaf(xv, swi[i * FH2 + ko], hi);
        hr = fmaf(xv, swr[i * FH2 + ko], hr);
    }
    h1[n * FH2 + ko] = hi;
    r1[n * FH2 + ko] = hr + b[ko];
}

// layer1 gather + relu + mean-over-K + dense2, all fused.
// 32 consecutive threads = one node (lane ko = k*16+f).
__global__ void k_gather1_mid(const int* __restrict__ inc, const int2* __restrict__ ecsr,
                              const float* __restrict__ h1, const float* __restrict__ r1,
                              const float* __restrict__ Wi2, const float* __restrict__ Wr2,
                              const float* __restrict__ b2,
                              float* __restrict__ h2, float* __restrict__ r2) {
    int tid = blockIdx.x * blockDim.x + threadIdx.x;
    int n = tid >> 5, ko = tid & 31;
    if (n >= NN) return;
    int js = (n == 0) ? 0 : inc[n - 1];
    int je = inc[n];
    float acc = r1[n * FH2 + ko];
    int j = js;
    for (; j + 1 < je; j += 2) {
        int2 e0 = ecsr[j], e1 = ecsr[j + 1];
        float v0 = h1[e0.x * FH2 + ko];
        float v1 = h1[e1.x * FH2 + ko];
        acc = fmaf(__int_as_float(e0.y), v0, acc);
        acc = fmaf(__int_as_float(e1.y), v1, acc);
    }
    if (j < je) {
        int2 e0 = ecsr[j];
        acc = fmaf(__int_as_float(e0.y), h1[e0.x * FH2 + ko], acc);
    }
    acc = fmaxf(acc, 0.f);                       // relu (layer out + wrapper relu)
    float h = 0.5f * (acc + __shfl_xor(acc, 16, 32));  // mean over K; lane ko holds h[ko&15]
    // dense2: lane's k = ko>>4, f = ko&15; Wi2/Wr2 flat layout [k*16+f] == [ko]
    float p1 = h * Wi2[ko];
    float p2 = h * Wr2[ko];
#pragma unroll
    for (int m = 1; m < 16; m <<= 1) {
        p1 += __shfl_xor(p1, m, 32);
        p2 += __shfl_xor(p2, m, 32);
    }
    if ((ko & 15) == 0) {
        int k = ko >> 4;
        h2[n * 2 + k] = p1;
        r2[n * 2 + k] = p2 + b2[k];
    }
}

// layer2 gather + final relu-mean
__global__ void k_gather2(const int* __restrict__ inc, const int2* __restrict__ ecsr,
                          const float* __restrict__ h2, const float* __restrict__ r2,
                          float* __restrict__ out) {
    int n = blockIdx.x * blockDim.x + threadIdx.x;
    if (n >= NN) return;
    int js = (n == 0) ? 0 : inc[n - 1];
    int je = inc[n];
    float a0 = r2[n * 2 + 0], a1v = r2[n * 2 + 1];
    int j = js;
    for (; j + 1 < je; j += 2) {
        int2 e0 = ecsr[j], e1 = ecsr[j + 1];
        float2 hv0 = *(const float2*)&h2[e0.x * 2];
        float2 hv1 = *(const float2*)&h2[e1.x * 2];
        float w0 = __int_as_float(e0.y), w1 = __int_as_float(e1.y);
        a0  = fmaf(w0, hv0.x, a0);  a1v = fmaf(w0, hv0.y, a1v);
        a0  = fmaf(w1, hv1.x, a0);  a1v = fmaf(w1, hv1.y, a1v);
    }
    if (j < je) {
        int2 e = ecsr[j];
        float w = __int_as_float(e.y);
        float2 hv = *(const float2*)&h2[e.x * 2];
        a0  = fmaf(w, hv.x, a0);
        a1v = fmaf(w, hv.y, a1v);
    }
    out[n] = 0.5f * (fmaxf(a0, 0.f) + fmaxf(a1v, 0.f));
}

extern "C" void kernel_launch(void* const* d_in, const int* in_sizes, int n_in,
                              void* d_out, int out_size, void* d_ws, size_t ws_size,
                              hipStream_t stream) {
    const float* x   = (const float*)d_in[0];
    const int*   ei  = (const int*)d_in[1];
    const float* Wi1 = (const float*)d_in[2];
    const float* Wr1 = (const float*)d_in[3];
    const float* b1  = (const float*)d_in[4];
    const float* Wi2 = (const float*)d_in[5];
    const float* Wr2 = (const float*)d_in[6];
    const float* b2  = (const float*)d_in[7];
    float* out = (float*)d_out;

    const int* row = ei;
    const int* col = ei + NE;

    int*   cnt  = (int*)d_ws;                        // NN
    int*   inc  = cnt + NN;                          // NN
    int*   bsum = inc + NN;                          // 128
    int*   boff = bsum + 128;                        // 128
    float* dis  = (float*)(boff + 128);              // NN
    int*   rank = (int*)(dis + NN);                  // NE
    int2*  ecsr = (int2*)(rank + NE);                // NE int2 (8B-aligned offset)
    float* h1   = (float*)(ecsr + NE);               // NN*32
    float* r1   = h1 + (size_t)NN * FH2;             // NN*32
    float* h2   = r1 + (size_t)NN * FH2;             // NN*2
    float* r2   = h2 + (size_t)NN * KS;              // NN*2

    const int B = 256;
    hipMemsetAsync(cnt, 0, (size_t)NN * sizeof(int), stream);
    k_count_rank<<<(NE + B - 1) / B, B, 0, stream>>>(col, cnt, rank);
    k_scan1<<<NSCAN, SCAN_B, 0, stream>>>(cnt, inc, bsum, dis);
    k_scan2<<<1, 128, 0, stream>>>(bsum, boff);
    k_scan3<<<(NN + B - 1) / B, B, 0, stream>>>(inc, boff);
    k_fill<<<(NE + B - 1) / B, B, 0, stream>>>(row, col, dis, inc, rank, ecsr);
    k_dense1<<<(NN + NODES_PER_BLK - 1) / NODES_PER_BLK, B, 0, stream>>>(x, Wi1, Wr1, b1, h1, r1);
    k_gather1_mid<<<(NN * 32 + B - 1) / B, B, 0, stream>>>(inc, ecsr, h1, r1, Wi2, Wr2, b2, h2, r2);
    k_gather2<<<(NN + B - 1) / B, B, 0, stream>>>(inc, ecsr, h2, r2, out);
}

// Round 4
// 222.661 us; speedup vs baseline: 4.3282x; 1.0226x over previous
//
#include <hip/hip_runtime.h>

#define NN 100000
#define NE 1600000

constexpr int F_IN = 58;
constexpr int F_H  = 16;
constexpr int KS   = 2;
constexpr int FH2  = 32;   // KS * F_H
constexpr int NODES_PER_BLK = 8;
constexpr int CPAD = 8;    // counter padding: 1 int per 32B sector

constexpr int SCAN_B = 256;
constexpr int SCAN_E = 1024;
constexpr int NSCAN  = (NN + SCAN_E - 1) / SCAN_E;  // 98

// histogram of destinations (padded counters); atomic return = rank within dst
__global__ void k_count_rank(const int* __restrict__ col, int* __restrict__ cntp,
                             int* __restrict__ rank) {
    int e = blockIdx.x * blockDim.x + threadIdx.x;
    if (e < NE) rank[e] = atomicAdd(&cntp[(size_t)col[e] * CPAD], 1);
}

// inclusive scan stage 1 over padded counters (+ fused dis = rsqrt(deg))
__global__ void k_scan1(const int* __restrict__ cntp, int* __restrict__ inc,
                        int* __restrict__ bsum, float* __restrict__ dis) {
    __shared__ int ts[SCAN_B];
    int tid = threadIdx.x;
    int base = blockIdx.x * SCAN_E + tid * 4;
    int v0 = (base + 0 < NN) ? cntp[(size_t)(base + 0) * CPAD] : 0;
    int v1 = (base + 1 < NN) ? cntp[(size_t)(base + 1) * CPAD] : 0;
    int v2 = (base + 2 < NN) ? cntp[(size_t)(base + 2) * CPAD] : 0;
    int v3 = (base + 3 < NN) ? cntp[(size_t)(base + 3) * CPAD] : 0;
    if (base + 0 < NN) dis[base + 0] = (v0 > 0) ? rsqrtf((float)v0) : 0.f;
    if (base + 1 < NN) dis[base + 1] = (v1 > 0) ? rsqrtf((float)v1) : 0.f;
    if (base + 2 < NN) dis[base + 2] = (v2 > 0) ? rsqrtf((float)v2) : 0.f;
    if (base + 3 < NN) dis[base + 3] = (v3 > 0) ? rsqrtf((float)v3) : 0.f;
    int p0 = v0, p1 = p0 + v1, p2 = p1 + v2, p3 = p2 + v3;
    ts[tid] = p3;
    __syncthreads();
    for (int off = 1; off < SCAN_B; off <<= 1) {
        int v = (tid >= off) ? ts[tid - off] : 0;
        __syncthreads();
        ts[tid] += v;
        __syncthreads();
    }
    int prev = (tid > 0) ? ts[tid - 1] : 0;
    if (base + 0 < NN) inc[base + 0] = prev + p0;
    if (base + 1 < NN) inc[base + 1] = prev + p1;
    if (base + 2 < NN) inc[base + 2] = prev + p2;
    if (base + 3 < NN) inc[base + 3] = prev + p3;
    if (tid == SCAN_B - 1) bsum[blockIdx.x] = ts[SCAN_B - 1];
}

__global__ void k_scan2(const int* __restrict__ bsum, int* __restrict__ boff) {
    __shared__ int s[128];
    int tid = threadIdx.x;
    s[tid] = (tid < NSCAN) ? bsum[tid] : 0;
    __syncthreads();
    for (int off = 1; off < 128; off <<= 1) {
        int v = (tid >= off) ? s[tid - off] : 0;
        __syncthreads();
        s[tid] += v;
        __syncthreads();
    }
    if (tid < NSCAN) boff[tid] = (tid > 0) ? s[tid - 1] : 0;
}

__global__ void k_scan3(int* __restrict__ inc, const int* __restrict__ boff) {
    int i = blockIdx.x * blockDim.x + threadIdx.x;
    if (i < NN) inc[i] += boff[i >> 10];
}

// CSR fill: no atomics, 4B payload (src only)
__global__ void k_fill(const int* __restrict__ row, const int* __restrict__ col,
                       const int* __restrict__ inc, const int* __restrict__ rank,
                       int* __restrict__ esrc) {
    int e = blockIdx.x * blockDim.x + threadIdx.x;
    if (e >= NE) return;
    int c = col[e];
    int pos = ((c == 0) ? 0 : inc[c - 1]) + rank[e];
    esrc[pos] = row[e];
}

// h1[n][ko] = x[n]·Wi[k][:,o];  r1[n][ko] = x[n]·Wr[k][:,o] + b[k][o]
__global__ void k_dense1(const float* __restrict__ x,
                         const float* __restrict__ Wi, const float* __restrict__ Wr,
                         const float* __restrict__ b,
                         float* __restrict__ h1, float* __restrict__ r1) {
    __shared__ float swi[F_IN * FH2];
    __shared__ float swr[F_IN * FH2];
    __shared__ float sx[NODES_PER_BLK * F_IN];
    int tid = threadIdx.x;
    for (int t = tid; t < F_IN * FH2; t += 256) {
        int i = t >> 5, ko = t & 31;
        int k = ko >> 4, o = ko & 15;
        swi[t] = Wi[(k * F_IN + i) * F_H + o];
        swr[t] = Wr[(k * F_IN + i) * F_H + o];
    }
    int nodeBase = blockIdx.x * NODES_PER_BLK;
    for (int t = tid; t < NODES_PER_BLK * F_IN; t += 256) {
        int ln = t / F_IN, i = t - ln * F_IN;
        int n = nodeBase + ln;
        sx[t] = (n < NN) ? x[n * F_IN + i] : 0.f;
    }
    __syncthreads();
    int ln = tid >> 5, ko = tid & 31;
    int n = nodeBase + ln;
    if (n >= NN) return;
    float hi = 0.f, hr = 0.f;
    const float* xr = &sx[ln * F_IN];
#pragma unroll
    for (int i = 0; i < F_IN; i++) {
        float xv = xr[i];
        hi = fmaf(xv, swi[i * FH2 + ko], hi);
        hr = fmaf(xv, swr[i * FH2 + ko], hr);
    }
    h1[n * FH2 + ko] = hi;
    r1[n * FH2 + ko] = hr + b[ko];
}

// layer1 gather + relu + mean-over-K + dense2, fused.
// 32 consecutive threads = one node (lane ko = k*16+f).
__global__ void k_gather1_mid(const int* __restrict__ inc, const int* __restrict__ esrc,
                              const float* __restrict__ dis,
                              const float* __restrict__ h1, const float* __restrict__ r1,
                              const float* __restrict__ Wi2, const float* __restrict__ Wr2,
                              const float* __restrict__ b2,
                              float* __restrict__ h2, float* __restrict__ r2) {
    int tid = blockIdx.x * blockDim.x + threadIdx.x;
    int n = tid >> 5, ko = tid & 31;
    if (n >= NN) return;
    int js = (n == 0) ? 0 : inc[n - 1];
    int je = inc[n];
    float dn = dis[n];
    float acc = r1[n * FH2 + ko];
    int j = js;
    for (; j + 1 < je; j += 2) {
        int s0 = esrc[j], s1 = esrc[j + 1];
        float w0 = dis[s0], w1 = dis[s1];
        float v0 = h1[(size_t)s0 * FH2 + ko];
        float v1 = h1[(size_t)s1 * FH2 + ko];
        acc = fmaf(w0 * dn, v0, acc);
        acc = fmaf(w1 * dn, v1, acc);
    }
    if (j < je) {
        int s0 = esrc[j];
        acc = fmaf(dis[s0] * dn, h1[(size_t)s0 * FH2 + ko], acc);
    }
    acc = fmaxf(acc, 0.f);                              // relu (layer + wrapper)
    float h = 0.5f * (acc + __shfl_xor(acc, 16, 32));   // mean over K
    float p1 = h * Wi2[ko];
    float p2 = h * Wr2[ko];
#pragma unroll
    for (int m = 1; m < 16; m <<= 1) {
        p1 += __shfl_xor(p1, m, 32);
        p2 += __shfl_xor(p2, m, 32);
    }
    if ((ko & 15) == 0) {
        int k = ko >> 4;
        h2[n * 2 + k] = p1;
        r2[n * 2 + k] = p2 + b2[k];
    }
}

// layer2 gather + final relu-mean
__global__ void k_gather2(const int* __restrict__ inc, const int* __restrict__ esrc,
                          const float* __restrict__ dis,
                          const float* __restrict__ h2, const float* __restrict__ r2,
                          float* __restrict__ out) {
    int n = blockIdx.x * blockDim.x + threadIdx.x;
    if (n >= NN) return;
    int js = (n == 0) ? 0 : inc[n - 1];
    int je = inc[n];
    float dn = dis[n];
    float a0 = r2[n * 2 + 0], a1v = r2[n * 2 + 1];
    int j = js;
    for (; j + 1 < je; j += 2) {
        int s0 = esrc[j], s1 = esrc[j + 1];
        float w0 = dis[s0] * dn, w1 = dis[s1] * dn;
        float2 hv0 = *(const float2*)&h2[(size_t)s0 * 2];
        float2 hv1 = *(const float2*)&h2[(size_t)s1 * 2];
        a0  = fmaf(w0, hv0.x, a0);  a1v = fmaf(w0, hv0.y, a1v);
        a0  = fmaf(w1, hv1.x, a0);  a1v = fmaf(w1, hv1.y, a1v);
    }
    if (j < je) {
        int s = esrc[j];
        float w = dis[s] * dn;
        float2 hv = *(const float2*)&h2[(size_t)s * 2];
        a0  = fmaf(w, hv.x, a0);
        a1v = fmaf(w, hv.y, a1v);
    }
    out[n] = 0.5f * (fmaxf(a0, 0.f) + fmaxf(a1v, 0.f));
}

extern "C" void kernel_launch(void* const* d_in, const int* in_sizes, int n_in,
                              void* d_out, int out_size, void* d_ws, size_t ws_size,
                              hipStream_t stream) {
    const float* x   = (const float*)d_in[0];
    const int*   ei  = (const int*)d_in[1];
    const float* Wi1 = (const float*)d_in[2];
    const float* Wr1 = (const float*)d_in[3];
    const float* b1  = (const float*)d_in[4];
    const float* Wi2 = (const float*)d_in[5];
    const float* Wr2 = (const float*)d_in[6];
    const float* b2  = (const float*)d_in[7];
    float* out = (float*)d_out;

    const int* row = ei;
    const int* col = ei + NE;

    int*   cntp = (int*)d_ws;                        // NN * CPAD (3.2 MB)
    int*   inc  = cntp + (size_t)NN * CPAD;          // NN
    int*   bsum = inc + NN;                          // 128
    int*   boff = bsum + 128;                        // 128
    float* dis  = (float*)(boff + 128);              // NN
    int*   rank = (int*)(dis + NN);                  // NE
    int*   esrc = rank + NE;                         // NE
    float* h1   = (float*)(esrc + NE);               // NN*32
    float* r1   = h1 + (size_t)NN * FH2;             // NN*32
    float* h2   = r1 + (size_t)NN * FH2;             // NN*2
    float* r2   = h2 + (size_t)NN * KS;              // NN*2

    const int B = 256;
    hipMemsetAsync(cntp, 0, (size_t)NN * CPAD * sizeof(int), stream);
    k_count_rank<<<(NE + B - 1) / B, B, 0, stream>>>(col, cntp, rank);
    k_scan1<<<NSCAN, SCAN_B, 0, stream>>>(cntp, inc, bsum, dis);
    k_scan2<<<1, 128, 0, stream>>>(bsum, boff);
    k_scan3<<<(NN + B - 1) / B, B, 0, stream>>>(inc, boff);
    k_fill<<<(NE + B - 1) / B, B, 0, stream>>>(row, col, inc, rank, esrc);
    k_dense1<<<(NN + NODES_PER_BLK - 1) / NODES_PER_BLK, B, 0, stream>>>(x, Wi1, Wr1, b1, h1, r1);
    k_gather1_mid<<<(NN * 32 + B - 1) / B, B, 0, stream>>>(inc, esrc, dis, h1, r1, Wi2, Wr2, b2, h2, r2);
    k_gather2<<<(NN + B - 1) / B, B, 0, stream>>>(inc, esrc, dis, h2, r2, out);
}

// Round 5
// 164.634 us; speedup vs baseline: 5.8537x; 1.3525x over previous
//
#include <hip/hip_runtime.h>

#define NN 100000
#define NE 1600000

constexpr int F_IN = 58;
constexpr int F_H  = 16;
constexpr int KS   = 2;
constexpr int FH2  = 32;            // KS * F_H
constexpr int NODES_PER_BLK = 8;

constexpr int NB   = 391;           // buckets: col >> 8 (99999>>8 = 390)
constexpr int NBLK = 256;           // phase-1 blocks
constexpr int EPB  = NE / NBLK;     // 6250 edges per block
constexpr int SCANN = NB * NBLK;    // 100096 (bucket-major matrix, flattened)
constexpr int SCAN_BLOCKS = (SCANN + 1023) / 1024;  // 98
constexpr int DENSE_BLOCKS = (NN + NODES_PER_BLK - 1) / NODES_PER_BLK;  // 12500

// blocks [0,NBLK): per-block bucket histogram (LDS atomics only).
// blocks [NBLK,...): dense layer-1 (independent work fused in to overlap).
__global__ void k_hist_dense1(const int* __restrict__ col, int* __restrict__ bh,
                              const float* __restrict__ x,
                              const float* __restrict__ Wi, const float* __restrict__ Wr,
                              const float* __restrict__ b,
                              float* __restrict__ h1, float* __restrict__ r1) {
    __shared__ float swi[F_IN * FH2];
    __shared__ float swr[F_IN * FH2];
    __shared__ float sx[NODES_PER_BLK * F_IN];
    __shared__ int hist[NB];
    int tid = threadIdx.x;

    if (blockIdx.x < NBLK) {
        int blk = blockIdx.x;
        for (int i = tid; i < NB; i += 256) hist[i] = 0;
        __syncthreads();
        int base = blk * EPB;
        for (int e = base + tid; e < base + EPB; e += 256)
            atomicAdd(&hist[col[e] >> 8], 1);
        __syncthreads();
        for (int i = tid; i < NB; i += 256)
            bh[i * NBLK + blk] = hist[i];   // bucket-major layout for the scan
        return;
    }

    // ---- dense1: h1 = x@Wi + 0, r1 = x@Wr + b ----
    for (int t = tid; t < F_IN * FH2; t += 256) {
        int i = t >> 5, ko = t & 31;
        int k = ko >> 4, o = ko & 15;
        swi[t] = Wi[(k * F_IN + i) * F_H + o];
        swr[t] = Wr[(k * F_IN + i) * F_H + o];
    }
    int nodeBase = (blockIdx.x - NBLK) * NODES_PER_BLK;
    for (int t = tid; t < NODES_PER_BLK * F_IN; t += 256) {
        int ln = t / F_IN, i = t - ln * F_IN;
        int n = nodeBase + ln;
        sx[t] = (n < NN) ? x[n * F_IN + i] : 0.f;
    }
    __syncthreads();
    int ln = tid >> 5, ko = tid & 31;
    int n = nodeBase + ln;
    if (n >= NN) return;
    float hi = 0.f, hr = 0.f;
    const float* xr = &sx[ln * F_IN];
#pragma unroll
    for (int i = 0; i < F_IN; i++) {
        float xv = xr[i];
        hi = fmaf(xv, swi[i * FH2 + ko], hi);
        hr = fmaf(xv, swr[i * FH2 + ko], hr);
    }
    h1[n * FH2 + ko] = hi;
    r1[n * FH2 + ko] = hr + b[ko];
}

// inclusive scan over bh[SCANN], in place; 1024 elems per block
__global__ void k_scan1(int* __restrict__ bh, int* __restrict__ bsum) {
    __shared__ int ts[256];
    int tid = threadIdx.x;
    int base = blockIdx.x * 1024 + tid * 4;
    int v0 = (base + 0 < SCANN) ? bh[base + 0] : 0;
    int v1 = (base + 1 < SCANN) ? bh[base + 1] : 0;
    int v2 = (base + 2 < SCANN) ? bh[base + 2] : 0;
    int v3 = (base + 3 < SCANN) ? bh[base + 3] : 0;
    int p0 = v0, p1 = p0 + v1, p2 = p1 + v2, p3 = p2 + v3;
    ts[tid] = p3;
    __syncthreads();
    for (int off = 1; off < 256; off <<= 1) {
        int v = (tid >= off) ? ts[tid - off] : 0;
        __syncthreads();
        ts[tid] += v;
        __syncthreads();
    }
    int prev = (tid > 0) ? ts[tid - 1] : 0;
    if (base + 0 < SCANN) bh[base + 0] = prev + p0;
    if (base + 1 < SCANN) bh[base + 1] = prev + p1;
    if (base + 2 < SCANN) bh[base + 2] = prev + p2;
    if (base + 3 < SCANN) bh[base + 3] = prev + p3;
    if (tid == 255) bsum[blockIdx.x] = ts[255];
}

__global__ void k_scan2(const int* __restrict__ bsum, int* __restrict__ boff) {
    __shared__ int s[128];
    int tid = threadIdx.x;
    s[tid] = (tid < SCAN_BLOCKS) ? bsum[tid] : 0;
    __syncthreads();
    for (int off = 1; off < 128; off <<= 1) {
        int v = (tid >= off) ? s[tid - off] : 0;
        __syncthreads();
        s[tid] += v;
        __syncthreads();
    }
    if (tid < SCAN_BLOCKS) boff[tid] = (tid > 0) ? s[tid - 1] : 0;
}

__global__ void k_scan3(int* __restrict__ bh, const int* __restrict__ boff) {
    int i = blockIdx.x * blockDim.x + threadIdx.x;
    if (i < SCANN) bh[i] += boff[i >> 10];
}

// scatter edges into bucket-major order; cursor per bucket in LDS (no global atomics)
__global__ void k_bscatter(const int* __restrict__ row, const int* __restrict__ col,
                           const int* __restrict__ bh, int* __restrict__ ebuck) {
    __shared__ int cur[NB];
    int tid = threadIdx.x, blk = blockIdx.x;
    for (int i = tid; i < NB; i += 256) {
        int idx = i * NBLK + blk;
        cur[i] = (idx == 0) ? 0 : bh[idx - 1];   // exclusive start for (bucket i, this block)
    }
    __syncthreads();
    int base = blk * EPB;
    for (int e = base + tid; e < base + EPB; e += 256) {
        int c = col[e];
        int pos = atomicAdd(&cur[c >> 8], 1);
        ebuck[pos] = (row[e] << 8) | (c & 255);   // packed (src, col-low-8)
    }
}

// one block per bucket: exact per-col counts + ranks in LDS -> CSR esrc, inc, dis
__global__ void __launch_bounds__(256) k_bcsr(const int* __restrict__ bh,
                                              const int* __restrict__ ebuck,
                                              int* __restrict__ esrc, int* __restrict__ inc,
                                              float* __restrict__ dis) {
    __shared__ int cnt[256];
    __shared__ int scn[256];
    __shared__ int cur[256];
    int b = blockIdx.x, tid = threadIdx.x;
    int start = (b == 0) ? 0 : bh[b * NBLK - 1];
    int end   = bh[(b + 1) * NBLK - 1];
    cnt[tid] = 0;
    __syncthreads();
    for (int j = start + tid; j < end; j += 256)
        atomicAdd(&cnt[ebuck[j] & 255], 1);
    __syncthreads();
    int v = cnt[tid];
    scn[tid] = v;
    __syncthreads();
    for (int off = 1; off < 256; off <<= 1) {
        int t = (tid >= off) ? scn[tid - off] : 0;
        __syncthreads();
        scn[tid] += t;
        __syncthreads();
    }
    int incl = scn[tid];
    cur[tid] = start + incl - v;          // exclusive
    int colIdx = (b << 8) + tid;
    if (colIdx < NN) {
        inc[colIdx] = start + incl;       // inclusive CSR end
        dis[colIdx] = (v > 0) ? rsqrtf((float)v) : 0.f;
    }
    __syncthreads();
    for (int j = start + tid; j < end; j += 256) {
        int e = ebuck[j];
        int pos = atomicAdd(&cur[e & 255], 1);
        esrc[pos] = e >> 8;
    }
}

// layer1 gather + relu + mean-over-K + dense2, fused. 32 threads = one node.
__global__ void k_gather1_mid(const int* __restrict__ inc, const int* __restrict__ esrc,
                              const float* __restrict__ dis,
                              const float* __restrict__ h1, const float* __restrict__ r1,
                              const float* __restrict__ Wi2, const float* __restrict__ Wr2,
                              const float* __restrict__ b2,
                              float* __restrict__ h2, float* __restrict__ r2) {
    int tid = blockIdx.x * blockDim.x + threadIdx.x;
    int n = tid >> 5, ko = tid & 31;
    if (n >= NN) return;
    int js = (n == 0) ? 0 : inc[n - 1];
    int je = inc[n];
    float dn = dis[n];
    float acc = r1[n * FH2 + ko];
    int j = js;
    for (; j + 1 < je; j += 2) {
        int s0 = esrc[j], s1 = esrc[j + 1];
        float w0 = dis[s0], w1 = dis[s1];
        float v0 = h1[(size_t)s0 * FH2 + ko];
        float v1 = h1[(size_t)s1 * FH2 + ko];
        acc = fmaf(w0 * dn, v0, acc);
        acc = fmaf(w1 * dn, v1, acc);
    }
    if (j < je) {
        int s0 = esrc[j];
        acc = fmaf(dis[s0] * dn, h1[(size_t)s0 * FH2 + ko], acc);
    }
    acc = fmaxf(acc, 0.f);                              // relu (layer + wrapper)
    float h = 0.5f * (acc + __shfl_xor(acc, 16, 32));   // mean over K
    float p1 = h * Wi2[ko];
    float p2 = h * Wr2[ko];
#pragma unroll
    for (int m = 1; m < 16; m <<= 1) {
        p1 += __shfl_xor(p1, m, 32);
        p2 += __shfl_xor(p2, m, 32);
    }
    if ((ko & 15) == 0) {
        int k = ko >> 4;
        h2[n * 2 + k] = p1;
        r2[n * 2 + k] = p2 + b2[k];
    }
}

// layer2 gather + final relu-mean
__global__ void k_gather2(const int* __restrict__ inc, const int* __restrict__ esrc,
                          const float* __restrict__ dis,
                          const float* __restrict__ h2, const float* __restrict__ r2,
                          float* __restrict__ out) {
    int n = blockIdx.x * blockDim.x + threadIdx.x;
    if (n >= NN) return;
    int js = (n == 0) ? 0 : inc[n - 1];
    int je = inc[n];
    float dn = dis[n];
    float a0 = r2[n * 2 + 0], a1v = r2[n * 2 + 1];
    int j = js;
    for (; j + 1 < je; j += 2) {
        int s0 = esrc[j], s1 = esrc[j + 1];
        float w0 = dis[s0] * dn, w1 = dis[s1] * dn;
        float2 hv0 = *(const float2*)&h2[(size_t)s0 * 2];
        float2 hv1 = *(const float2*)&h2[(size_t)s1 * 2];
        a0  = fmaf(w0, hv0.x, a0);  a1v = fmaf(w0, hv0.y, a1v);
        a0  = fmaf(w1, hv1.x, a0);  a1v = fmaf(w1, hv1.y, a1v);
    }
    if (j < je) {
        int s = esrc[j];
        float w = dis[s] * dn;
        float2 hv = *(const float2*)&h2[(size_t)s * 2];
        a0  = fmaf(w, hv.x, a0);
        a1v = fmaf(w, hv.y, a1v);
    }
    out[n] = 0.5f * (fmaxf(a0, 0.f) + fmaxf(a1v, 0.f));
}

extern "C" void kernel_launch(void* const* d_in, const int* in_sizes, int n_in,
                              void* d_out, int out_size, void* d_ws, size_t ws_size,
                              hipStream_t stream) {
    const float* x   = (const float*)d_in[0];
    const int*   ei  = (const int*)d_in[1];
    const float* Wi1 = (const float*)d_in[2];
    const float* Wr1 = (const float*)d_in[3];
    const float* b1  = (const float*)d_in[4];
    const float* Wi2 = (const float*)d_in[5];
    const float* Wr2 = (const float*)d_in[6];
    const float* b2  = (const float*)d_in[7];
    float* out = (float*)d_out;

    const int* row = ei;
    const int* col = ei + NE;

    int*   bh    = (int*)d_ws;                       // SCANN (scanned in place)
    int*   bsum  = bh + SCANN;                       // 128
    int*   boff  = bsum + 128;                       // 128
    float* dis   = (float*)(boff + 128);             // NN
    int*   inc   = (int*)(dis + NN);                 // NN
    int*   ebuck = inc + NN;                         // NE (packed src<<8|col&255)
    int*   esrc  = ebuck + NE;                       // NE
    float* h1    = (float*)(esrc + NE);              // NN*32
    float* r1    = h1 + (size_t)NN * FH2;            // NN*32
    float* h2    = r1 + (size_t)NN * FH2;            // NN*2
    float* r2    = h2 + (size_t)NN * KS;             // NN*2

    const int B = 256;
    k_hist_dense1<<<NBLK + DENSE_BLOCKS, B, 0, stream>>>(col, bh, x, Wi1, Wr1, b1, h1, r1);
    k_scan1<<<SCAN_BLOCKS, B, 0, stream>>>(bh, bsum);
    k_scan2<<<1, 128, 0, stream>>>(bsum, boff);
    k_scan3<<<(SCANN + B - 1) / B, B, 0, stream>>>(bh, boff);
    k_bscatter<<<NBLK, B, 0, stream>>>(row, col, bh, ebuck);
    k_bcsr<<<NB, B, 0, stream>>>(bh, ebuck, esrc, inc, dis);
    k_gather1_mid<<<(NN * 32 + B - 1) / B, B, 0, stream>>>(inc, esrc, dis, h1, r1, Wi2, Wr2, b2, h2, r2);
    k_gather2<<<(NN + B - 1) / B, B, 0, stream>>>(inc, esrc, dis, h2, r2, out);
}

// Round 6
// 140.152 us; speedup vs baseline: 6.8762x; 1.1747x over previous
//
#include <hip/hip_runtime.h>

#define NN 100000
#define NE 1600000

constexpr int F_IN = 58;
constexpr int F_H  = 16;
constexpr int KS   = 2;
constexpr int FH2  = 32;            // KS * F_H
constexpr int NODES_PER_BLK = 8;

constexpr int NB   = 391;           // buckets: col >> 8 (99999>>8 = 390)
constexpr int NBLK = 256;           // phase-1 blocks
constexpr int EPB  = NE / NBLK;     // 6250 edges per block
constexpr int SCANN = NB * NBLK;    // 100096
constexpr int SCAN_BLOCKS = (SCANN + 1023) / 1024;  // 98
constexpr int DENSE_BLOCKS = (NN + NODES_PER_BLK - 1) / NODES_PER_BLK;  // 12500

// blocks [0,NBLK): per-block bucket histogram (LDS atomics only).
// blocks [NBLK,...): dense layer-1 (independent work fused in to overlap).
__global__ void k_hist_dense1(const int* __restrict__ col, int* __restrict__ bh,
                              const float* __restrict__ x,
                              const float* __restrict__ Wi, const float* __restrict__ Wr,
                              const float* __restrict__ b,
                              float* __restrict__ h1, float* __restrict__ r1) {
    __shared__ float swi[F_IN * FH2];
    __shared__ float swr[F_IN * FH2];
    __shared__ float sx[NODES_PER_BLK * F_IN];
    __shared__ int hist[NB];
    int tid = threadIdx.x;

    if (blockIdx.x < NBLK) {
        int blk = blockIdx.x;
        for (int i = tid; i < NB; i += 256) hist[i] = 0;
        __syncthreads();
        int base = blk * EPB;
        for (int e = base + tid; e < base + EPB; e += 256)
            atomicAdd(&hist[col[e] >> 8], 1);
        __syncthreads();
        for (int i = tid; i < NB; i += 256)
            bh[i * NBLK + blk] = hist[i];   // bucket-major for the scan
        return;
    }

    for (int t = tid; t < F_IN * FH2; t += 256) {
        int i = t >> 5, ko = t & 31;
        int k = ko >> 4, o = ko & 15;
        swi[t] = Wi[(k * F_IN + i) * F_H + o];
        swr[t] = Wr[(k * F_IN + i) * F_H + o];
    }
    int nodeBase = (blockIdx.x - NBLK) * NODES_PER_BLK;
    for (int t = tid; t < NODES_PER_BLK * F_IN; t += 256) {
        int ln = t / F_IN, i = t - ln * F_IN;
        int n = nodeBase + ln;
        sx[t] = (n < NN) ? x[n * F_IN + i] : 0.f;
    }
    __syncthreads();
    int ln = tid >> 5, ko = tid & 31;
    int n = nodeBase + ln;
    if (n >= NN) return;
    float hi = 0.f, hr = 0.f;
    const float* xr = &sx[ln * F_IN];
#pragma unroll
    for (int i = 0; i < F_IN; i++) {
        float xv = xr[i];
        hi = fmaf(xv, swi[i * FH2 + ko], hi);
        hr = fmaf(xv, swr[i * FH2 + ko], hr);
    }
    h1[n * FH2 + ko] = hi;
    r1[n * FH2 + ko] = hr + b[ko];
}

__global__ void k_scan1(int* __restrict__ bh, int* __restrict__ bsum) {
    __shared__ int ts[256];
    int tid = threadIdx.x;
    int base = blockIdx.x * 1024 + tid * 4;
    int v0 = (base + 0 < SCANN) ? bh[base + 0] : 0;
    int v1 = (base + 1 < SCANN) ? bh[base + 1] : 0;
    int v2 = (base + 2 < SCANN) ? bh[base + 2] : 0;
    int v3 = (base + 3 < SCANN) ? bh[base + 3] : 0;
    int p0 = v0, p1 = p0 + v1, p2 = p1 + v2, p3 = p2 + v3;
    ts[tid] = p3;
    __syncthreads();
    for (int off = 1; off < 256; off <<= 1) {
        int v = (tid >= off) ? ts[tid - off] : 0;
        __syncthreads();
        ts[tid] += v;
        __syncthreads();
    }
    int prev = (tid > 0) ? ts[tid - 1] : 0;
    if (base + 0 < SCANN) bh[base + 0] = prev + p0;
    if (base + 1 < SCANN) bh[base + 1] = prev + p1;
    if (base + 2 < SCANN) bh[base + 2] = prev + p2;
    if (base + 3 < SCANN) bh[base + 3] = prev + p3;
    if (tid == 255) bsum[blockIdx.x] = ts[255];
}

__global__ void k_scan2(const int* __restrict__ bsum, int* __restrict__ boff) {
    __shared__ int s[128];
    int tid = threadIdx.x;
    s[tid] = (tid < SCAN_BLOCKS) ? bsum[tid] : 0;
    __syncthreads();
    for (int off = 1; off < 128; off <<= 1) {
        int v = (tid >= off) ? s[tid - off] : 0;
        __syncthreads();
        s[tid] += v;
        __syncthreads();
    }
    if (tid < SCAN_BLOCKS) boff[tid] = (tid > 0) ? s[tid - 1] : 0;
}

__global__ void k_scan3(int* __restrict__ bh, const int* __restrict__ boff) {
    int i = blockIdx.x * blockDim.x + threadIdx.x;
    if (i < SCANN) bh[i] += boff[i >> 10];
}

__global__ void k_bscatter(const int* __restrict__ row, const int* __restrict__ col,
                           const int* __restrict__ bh, int* __restrict__ ebuck) {
    __shared__ int cur[NB];
    int tid = threadIdx.x, blk = blockIdx.x;
    for (int i = tid; i < NB; i += 256) {
        int idx = i * NBLK + blk;
        cur[i] = (idx == 0) ? 0 : bh[idx - 1];
    }
    __syncthreads();
    int base = blk * EPB;
    for (int e = base + tid; e < base + EPB; e += 256) {
        int c = col[e];
        int pos = atomicAdd(&cur[c >> 8], 1);
        ebuck[pos] = (row[e] << 8) | (c & 255);
    }
}

__global__ void __launch_bounds__(256) k_bcsr(const int* __restrict__ bh,
                                              const int* __restrict__ ebuck,
                                              int* __restrict__ esrc, int* __restrict__ inc,
                                              float* __restrict__ dis) {
    __shared__ int cnt[256];
    __shared__ int scn[256];
    __shared__ int cur[256];
    int b = blockIdx.x, tid = threadIdx.x;
    int start = (b == 0) ? 0 : bh[b * NBLK - 1];
    int end   = bh[(b + 1) * NBLK - 1];
    cnt[tid] = 0;
    __syncthreads();
    for (int j = start + tid; j < end; j += 256)
        atomicAdd(&cnt[ebuck[j] & 255], 1);
    __syncthreads();
    int v = cnt[tid];
    scn[tid] = v;
    __syncthreads();
    for (int off = 1; off < 256; off <<= 1) {
        int t = (tid >= off) ? scn[tid - off] : 0;
        __syncthreads();
        scn[tid] += t;
        __syncthreads();
    }
    int incl = scn[tid];
    cur[tid] = start + incl - v;
    int colIdx = (b << 8) + tid;
    if (colIdx < NN) {
        inc[colIdx] = start + incl;
        dis[colIdx] = (v > 0) ? rsqrtf((float)v) : 0.f;
    }
    __syncthreads();
    for (int j = start + tid; j < end; j += 256) {
        int e = ebuck[j];
        int pos = atomicAdd(&cur[e & 255], 1);
        esrc[pos] = e >> 8;
    }
}

// layer1 gather + relu + K-mean + dense2, fused. 8 lanes per node, float4 rows.
// lane l owns floats [l*4, l*4+4) of the 32-wide row; k = l>>2, f = (l&3)*4+i.
__global__ void k_gather1_mid(const int* __restrict__ inc, const int* __restrict__ esrc,
                              const float* __restrict__ dis,
                              const float4* __restrict__ h1, const float4* __restrict__ r1,
                              const float4* __restrict__ Wi2, const float4* __restrict__ Wr2,
                              const float* __restrict__ b2,
                              float* __restrict__ h2, float* __restrict__ r2) {
    int tid = blockIdx.x * blockDim.x + threadIdx.x;
    int n = tid >> 3, l = tid & 7;
    if (n >= NN) return;
    int js = (n == 0) ? 0 : inc[n - 1];
    int je = inc[n];
    float dn = dis[n];
    float4 acc = r1[(size_t)n * 8 + l];
    int j = js;
    for (; j + 1 < je; j += 2) {
        int s0 = esrc[j], s1 = esrc[j + 1];
        float w0 = dis[s0] * dn, w1 = dis[s1] * dn;
        float4 v0 = h1[(size_t)s0 * 8 + l];
        float4 v1 = h1[(size_t)s1 * 8 + l];
        acc.x = fmaf(w0, v0.x, acc.x); acc.y = fmaf(w0, v0.y, acc.y);
        acc.z = fmaf(w0, v0.z, acc.z); acc.w = fmaf(w0, v0.w, acc.w);
        acc.x = fmaf(w1, v1.x, acc.x); acc.y = fmaf(w1, v1.y, acc.y);
        acc.z = fmaf(w1, v1.z, acc.z); acc.w = fmaf(w1, v1.w, acc.w);
    }
    if (j < je) {
        int s0 = esrc[j];
        float w0 = dis[s0] * dn;
        float4 v0 = h1[(size_t)s0 * 8 + l];
        acc.x = fmaf(w0, v0.x, acc.x); acc.y = fmaf(w0, v0.y, acc.y);
        acc.z = fmaf(w0, v0.z, acc.z); acc.w = fmaf(w0, v0.w, acc.w);
    }
    // relu
    acc.x = fmaxf(acc.x, 0.f); acc.y = fmaxf(acc.y, 0.f);
    acc.z = fmaxf(acc.z, 0.f); acc.w = fmaxf(acc.w, 0.f);
    // mean over K: partner lane l^4 holds same f-range of the other stack
    float4 h;
    h.x = 0.5f * (acc.x + __shfl_xor(acc.x, 4));
    h.y = 0.5f * (acc.y + __shfl_xor(acc.y, 4));
    h.z = 0.5f * (acc.z + __shfl_xor(acc.z, 4));
    h.w = 0.5f * (acc.w + __shfl_xor(acc.w, 4));
    // dense2: W2 flat [k*16 + f] -> float4 index l (k=l>>2 lines up)
    float4 wi = Wi2[l], wr = Wr2[l];
    float p1 = h.x * wi.x + h.y * wi.y + h.z * wi.z + h.w * wi.w;
    float p2 = h.x * wr.x + h.y * wr.y + h.z * wr.z + h.w * wr.w;
    p1 += __shfl_xor(p1, 1); p1 += __shfl_xor(p1, 2);
    p2 += __shfl_xor(p2, 1); p2 += __shfl_xor(p2, 2);
    if ((l & 3) == 0) {
        int k = l >> 2;
        h2[n * 2 + k] = p1;
        r2[n * 2 + k] = p2 + b2[k];
    }
}

// layer2 gather: 8 lanes per node, edge-parallel; shfl-reduce, lane 0 finishes.
__global__ void k_gather2(const int* __restrict__ inc, const int* __restrict__ esrc,
                          const float* __restrict__ dis,
                          const float* __restrict__ h2, const float* __restrict__ r2,
                          float* __restrict__ out) {
    int tid = blockIdx.x * blockDim.x + threadIdx.x;
    int n = tid >> 3, l = tid & 7;
    if (n >= NN) return;
    int js = (n == 0) ? 0 : inc[n - 1];
    int je = inc[n];
    float dn = dis[n];
    float a0 = 0.f, a1v = 0.f;
    for (int j = js + l; j < je; j += 8) {
        int s = esrc[j];
        float w = dis[s] * dn;
        float2 hv = *(const float2*)&h2[(size_t)s * 2];
        a0  = fmaf(w, hv.x, a0);
        a1v = fmaf(w, hv.y, a1v);
    }
    a0  += __shfl_xor(a0, 1);  a0  += __shfl_xor(a0, 2);  a0  += __shfl_xor(a0, 4);
    a1v += __shfl_xor(a1v, 1); a1v += __shfl_xor(a1v, 2); a1v += __shfl_xor(a1v, 4);
    if (l == 0) {
        float2 rv = *(const float2*)&r2[(size_t)n * 2];
        out[n] = 0.5f * (fmaxf(a0 + rv.x, 0.f) + fmaxf(a1v + rv.y, 0.f));
    }
}

extern "C" void kernel_launch(void* const* d_in, const int* in_sizes, int n_in,
                              void* d_out, int out_size, void* d_ws, size_t ws_size,
                              hipStream_t stream) {
    const float* x   = (const float*)d_in[0];
    const int*   ei  = (const int*)d_in[1];
    const float* Wi1 = (const float*)d_in[2];
    const float* Wr1 = (const float*)d_in[3];
    const float* b1  = (const float*)d_in[4];
    const float* Wi2 = (const float*)d_in[5];
    const float* Wr2 = (const float*)d_in[6];
    const float* b2  = (const float*)d_in[7];
    float* out = (float*)d_out;

    const int* row = ei;
    const int* col = ei + NE;

    int*   bh    = (int*)d_ws;                       // SCANN
    int*   bsum  = bh + SCANN;                       // 128
    int*   boff  = bsum + 128;                       // 128
    float* dis   = (float*)(boff + 128);             // NN
    int*   inc   = (int*)(dis + NN);                 // NN
    int*   ebuck = inc + NN;                         // NE
    int*   esrc  = ebuck + NE;                       // NE
    float* h1    = (float*)(esrc + NE);              // NN*32 (16B aligned)
    float* r1    = h1 + (size_t)NN * FH2;            // NN*32
    float* h2    = r1 + (size_t)NN * FH2;            // NN*2
    float* r2    = h2 + (size_t)NN * KS;             // NN*2

    const int B = 256;
    k_hist_dense1<<<NBLK + DENSE_BLOCKS, B, 0, stream>>>(col, bh, x, Wi1, Wr1, b1, h1, r1);
    k_scan1<<<SCAN_BLOCKS, B, 0, stream>>>(bh, bsum);
    k_scan2<<<1, 128, 0, stream>>>(bsum, boff);
    k_scan3<<<(SCANN + B - 1) / B, B, 0, stream>>>(bh, boff);
    k_bscatter<<<NBLK, B, 0, stream>>>(row, col, bh, ebuck);
    k_bcsr<<<NB, B, 0, stream>>>(bh, ebuck, esrc, inc, dis);
    k_gather1_mid<<<(NN * 8 + B - 1) / B, B, 0, stream>>>(inc, esrc, dis,
        (const float4*)h1, (const float4*)r1, (const float4*)Wi2, (const float4*)Wr2,
        b2, h2, r2);
    k_gather2<<<(NN * 8 + B - 1) / B, B, 0, stream>>>(inc, esrc, dis, h2, r2, out);
}